// Round 5
// baseline (769.541 us; speedup 1.0000x reference)
//
#include <hip/hip_runtime.h>
#include <cstdint>

using f32x4 = __attribute__((ext_vector_type(4))) float;
using s16x8 = __attribute__((ext_vector_type(8))) short;
typedef unsigned short u16;

__device__ __forceinline__ u16 f2bf(float f) {
  union { float f; uint32_t u; } v; v.f = f;
  uint32_t r = v.u + 0x7FFFu + ((v.u >> 16) & 1u);  // RNE
  return (u16)(r >> 16);
}
__device__ __forceinline__ float bf2f(u16 b) {
  union { uint32_t u; float f; } v; v.u = ((uint32_t)b) << 16;
  return v.f;
}

// ---------------- k0: normalize prompts -> p_bf (bf16, padded to 1024 rows), ws[0,2MB)
__global__ __launch_bounds__(256) void k_prep_prompts(const float* __restrict__ prompts,
                                                      u16* __restrict__ p_bf) {
  const int r = blockIdx.x;   // 0..1023
  const int t = threadIdx.x;  // 256
  if (r >= 1000) {            // zero-fill pad rows
    if (t < 128) {
      s16x8 z = {0, 0, 0, 0, 0, 0, 0, 0};
      ((s16x8*)(p_bf + (size_t)r * 1024))[t] = z;
    }
    return;
  }
  float4 x = ((const float4*)(prompts + (size_t)r * 1024))[t];
  float ss = x.x * x.x + x.y * x.y + x.z * x.z + x.w * x.w;
  #pragma unroll
  for (int off = 32; off; off >>= 1) ss += __shfl_xor(ss, off);
  __shared__ float red[4];
  if ((t & 63) == 0) red[t >> 6] = ss;
  __syncthreads();
  float n = fmaxf(sqrtf(red[0] + red[1] + red[2] + red[3]), 1e-12f);
  float inv = 1.0f / n;
  u16* pb = p_bf + (size_t)r * 1024 + t * 4;
  pb[0] = f2bf(x.x * inv); pb[1] = f2bf(x.y * inv);
  pb[2] = f2bf(x.z * inv); pb[3] = f2bf(x.w * inv);
}

// ---------------- k1: bf16 MFMA GEMM  sims[n][c] = sum_k bf16(feat[n][k])*p_bf[c][k]
// 128x128 tile, BK=32, 4 waves (2x2 of 64x64), 16x16x32 MFMA, reg-staged A (fp32->bf16)
__global__ __launch_bounds__(256) void k_sims(const float* __restrict__ feat, // [65536][1024] f32
                                              const u16* __restrict__ B,      // [1024][1024] bf16
                                              u16* __restrict__ C) {          // [65536][1000] bf16
  __shared__ u16 As[128 * 32];
  __shared__ u16 Bs[128 * 32];
  const int bid = blockIdx.x;
  const int bn = bid & 7;   // col tile fastest: 8 consecutive blocks share one A-strip
  const int bm = bid >> 3;
  const int t = threadIdx.x;
  const int w = t >> 6, l = t & 63;
  const int wm = (w >> 1) * 64, wn = (w & 1) * 64;
  const int lrow = l & 15, lko = l >> 4;

  f32x4 zero4 = {0.f, 0.f, 0.f, 0.f};
  f32x4 acc[4][4];
  #pragma unroll
  for (int i = 0; i < 4; i++)
    #pragma unroll
    for (int j = 0; j < 4; j++) acc[i][j] = zero4;

  const int srow = t >> 1;        // 0..127
  const int scol = (t & 1) * 16;  // 0 or 16

  const float* gA = feat + (size_t)(bm * 128 + srow) * 1024 + scol;
  const u16* gB = B + (size_t)(bn * 128 + srow) * 1024 + scol;

  for (int k0 = 0; k0 < 1024; k0 += 32) {
    const float4* ga4 = (const float4*)(gA + k0);
    float4 f0 = ga4[0], f1 = ga4[1], f2 = ga4[2], f3 = ga4[3];
    const s16x8* gb8 = (const s16x8*)(gB + k0);
    s16x8 b0 = gb8[0], b1 = gb8[1];
    s16x8 a0, a1;
    a0[0] = (short)f2bf(f0.x); a0[1] = (short)f2bf(f0.y);
    a0[2] = (short)f2bf(f0.z); a0[3] = (short)f2bf(f0.w);
    a0[4] = (short)f2bf(f1.x); a0[5] = (short)f2bf(f1.y);
    a0[6] = (short)f2bf(f1.z); a0[7] = (short)f2bf(f1.w);
    a1[0] = (short)f2bf(f2.x); a1[1] = (short)f2bf(f2.y);
    a1[2] = (short)f2bf(f2.z); a1[3] = (short)f2bf(f2.w);
    a1[4] = (short)f2bf(f3.x); a1[5] = (short)f2bf(f3.y);
    a1[6] = (short)f2bf(f3.z); a1[7] = (short)f2bf(f3.w);
    __syncthreads();
    *(s16x8*)&As[srow * 32 + scol] = a0;
    *(s16x8*)&As[srow * 32 + scol + 8] = a1;
    *(s16x8*)&Bs[srow * 32 + scol] = b0;
    *(s16x8*)&Bs[srow * 32 + scol + 8] = b1;
    __syncthreads();
    s16x8 a[4], b[4];
    #pragma unroll
    for (int mi = 0; mi < 4; mi++) a[mi] = *(const s16x8*)&As[(wm + mi * 16 + lrow) * 32 + lko * 8];
    #pragma unroll
    for (int ni = 0; ni < 4; ni++) b[ni] = *(const s16x8*)&Bs[(wn + ni * 16 + lrow) * 32 + lko * 8];
    #pragma unroll
    for (int mi = 0; mi < 4; mi++)
      #pragma unroll
      for (int ni = 0; ni < 4; ni++)
        acc[mi][ni] = __builtin_amdgcn_mfma_f32_16x16x32_bf16(a[mi], b[ni], acc[mi][ni], 0, 0, 0);
  }
  const int rbase = (l >> 4) * 4;
  #pragma unroll
  for (int mi = 0; mi < 4; mi++)
    #pragma unroll
    for (int ni = 0; ni < 4; ni++) {
      int gcol = bn * 128 + wn + ni * 16 + lrow;
      if (gcol >= 1000) continue;
      #pragma unroll
      for (int j = 0; j < 4; j++) {
        int grow = bm * 128 + wm + mi * 16 + rbase + j;
        C[(size_t)grow * 1000 + gcol] = f2bf(acc[mi][ni][j]);
      }
    }
}

// ---------------- k2: per-row top-8 screen + exact rescore + top-2 -> compact results in ws
__global__ __launch_bounds__(256) void k_topk(const float* __restrict__ feat,
                                              const float* __restrict__ prompts,
                                              const u16* __restrict__ sims,
                                              int2* __restrict__ resc,
                                              float2* __restrict__ resw) {
  const int l = threadIdx.x & 63;
  const int row = blockIdx.x * 4 + (threadIdx.x >> 6);
  const u16* srow_p = sims + (size_t)row * 1000;
  const float NEG = -3.0e38f;
  // strided sims load: lane l owns cols {l, l+64, ..., l+960}
  float s[16];
  #pragma unroll
  for (int jj = 0; jj < 16; jj++) {
    int c = l + 64 * jj;
    s[jj] = (c < 1000) ? bf2f(srow_p[c]) : NEG;
  }
  // top-8 by staged sims (tie -> lower col)
  int cand[8];
  uint32_t taken = 0;
  #pragma unroll
  for (int it = 0; it < 8; it++) {
    float bv = NEG; int bj = 0;
    #pragma unroll
    for (int j = 0; j < 16; j++) {
      bool ok = !((taken >> j) & 1u) && (s[j] > bv);
      if (ok) { bv = s[j]; bj = j; }
    }
    int bc = l + 64 * bj;
    #pragma unroll
    for (int off = 32; off; off >>= 1) {
      float ov = __shfl_xor(bv, off);
      int oc = __shfl_xor(bc, off);
      if (ov > bv || (ov == bv && oc < bc)) { bv = ov; bc = oc; }
    }
    cand[it] = (bc < 1000) ? bc : 999;
    if ((bc & 63) == l) taken |= (1u << (bc >> 6));
  }
  // feat row, norm
  const int base = l * 16;
  float q[16];
  const float4* fr = (const float4*)(feat + (size_t)row * 1024 + base);
  #pragma unroll
  for (int g = 0; g < 4; g++) {
    float4 x = fr[g];
    q[g * 4 + 0] = x.x; q[g * 4 + 1] = x.y; q[g * 4 + 2] = x.z; q[g * 4 + 3] = x.w;
  }
  float qq = 0.f;
  #pragma unroll
  for (int e = 0; e < 16; e++) qq += q[e] * q[e];
  #pragma unroll
  for (int off = 32; off; off >>= 1) qq += __shfl_xor(qq, off);
  float rn = 1.0f / fmaxf(sqrtf(qq), 1e-12f);
  // exact fp32 rescore (raw prompts, on-the-fly norm)
  float sc[8];
  #pragma unroll
  for (int i = 0; i < 8; i++) {
    const float4* pr = (const float4*)(prompts + (size_t)cand[i] * 1024 + base);
    float d = 0.f, nn = 0.f;
    #pragma unroll
    for (int g = 0; g < 4; g++) {
      float4 x = pr[g];
      d += q[g * 4 + 0] * x.x; d += q[g * 4 + 1] * x.y;
      d += q[g * 4 + 2] * x.z; d += q[g * 4 + 3] * x.w;
      nn += x.x * x.x + x.y * x.y + x.z * x.z + x.w * x.w;
    }
    #pragma unroll
    for (int off = 32; off; off >>= 1) {
      d += __shfl_xor(d, off);
      nn += __shfl_xor(nn, off);
    }
    sc[i] = d * rn / fmaxf(sqrtf(nn), 1e-12f);
  }
  // top-2 among exact scores (tie -> lower class index)
  int i1 = 0;
  #pragma unroll
  for (int i = 1; i < 8; i++)
    if (sc[i] > sc[i1] || (sc[i] == sc[i1] && cand[i] < cand[i1])) i1 = i;
  int i2 = (i1 == 0) ? 1 : 0;
  #pragma unroll
  for (int i = 0; i < 8; i++) {
    if (i == i1) continue;
    if (sc[i] > sc[i2] || (sc[i] == sc[i2] && cand[i] < cand[i2])) i2 = i;
  }
  int c1 = cand[i1], c2 = cand[i2];
  float e = expf(fminf(sc[i2] - sc[i1], 0.0f) * (1.0f / 0.07f));  // (0,1]
  float w1 = 1.0f / (1.0f + e);
  float w2 = e / (1.0f + e);
  if (l == 0) {
    resc[row] = make_int2(c1, c2);
    resw[row] = make_float2(w1, w2);
  }
}

// ---------------- k3: expand results -> float32 outputs (one block per row)
__global__ __launch_bounds__(256) void k_write(const float* __restrict__ prompts,
                                               const int2* __restrict__ resc,
                                               const float2* __restrict__ resw,
                                               float* __restrict__ mixed,
                                               float* __restrict__ probs) {
  const int row = blockIdx.x;
  const int t = threadIdx.x;
  int2 cc = resc[row];
  float2 ww = resw[row];
  // mixed row: 256 threads x float4 = 1024 floats
  const float4* P1 = (const float4*)(prompts + (size_t)cc.x * 1024);
  const float4* P2 = (const float4*)(prompts + (size_t)cc.y * 1024);
  float4 a = P1[t], b = P2[t];
  float4 o;
  o.x = ww.x * a.x + ww.y * b.x;
  o.y = ww.x * a.y + ww.y * b.y;
  o.z = ww.x * a.z + ww.y * b.z;
  o.w = ww.x * a.w + ww.y * b.w;
  ((float4*)(mixed + (size_t)row * 1024))[t] = o;
  // probs row: 250 float4 = 1000 floats, zeros + two weights
  if (t < 250) {
    const int base = t * 4;
    float4 z;
    z.x = (base + 0 == cc.x) ? ww.x : ((base + 0 == cc.y) ? ww.y : 0.0f);
    z.y = (base + 1 == cc.x) ? ww.x : ((base + 1 == cc.y) ? ww.y : 0.0f);
    z.z = (base + 2 == cc.x) ? ww.x : ((base + 2 == cc.y) ? ww.y : 0.0f);
    z.w = (base + 3 == cc.x) ? ww.x : ((base + 3 == cc.y) ? ww.y : 0.0f);
    ((float4*)(probs + (size_t)row * 1000))[t] = z;
  }
}

extern "C" void kernel_launch(void* const* d_in, const int* in_sizes, int n_in,
                              void* d_out, int out_size, void* d_ws, size_t ws_size,
                              hipStream_t stream) {
  // identify inputs by element count, not position
  int fi = 0, pi = 1;
  for (int i = 0; i < n_in; i++) {
    if (in_sizes[i] == 67108864) fi = i;
    else if (in_sizes[i] == 1024000) pi = i;
  }
  const float* feat = (const float*)d_in[fi];
  const float* prompts = (const float*)d_in[pi];

  // outputs are FLOAT32: mixed [65536*1024], probs [65536*1000]
  float* mixed = (float*)d_out;
  float* probs = mixed + 67108864ull;

  // ws: [0,2MB) bf16 prompt table; [2MB,2.5MB) int2 per-row classes; [2.5MB,3MB) float2 weights
  u16* p_bf = (u16*)d_ws;
  int2* resc = (int2*)((char*)d_ws + (2ull << 20));
  float2* resw = (float2*)((char*)d_ws + (2ull << 20) + (512ull << 10));

  // bf16 sims staged at the start of d_out (mixed region scratch; rewritten by k_write later)
  u16* sims = (u16*)d_out;

  hipLaunchKernelGGL(k_prep_prompts, dim3(1024), dim3(256), 0, stream, prompts, p_bf);
  hipLaunchKernelGGL(k_sims, dim3(4096), dim3(256), 0, stream, feat, p_bf, sims);
  hipLaunchKernelGGL(k_topk, dim3(16384), dim3(256), 0, stream, feat, prompts, sims, resc, resw);
  hipLaunchKernelGGL(k_write, dim3(65536), dim3(256), 0, stream, prompts, resc, resw, mixed, probs);
}

// Round 6
// 713.559 us; speedup vs baseline: 1.0785x; 1.0785x over previous
//
#include <hip/hip_runtime.h>
#include <cstdint>

using f32x4 = __attribute__((ext_vector_type(4))) float;
using s16x8 = __attribute__((ext_vector_type(8))) short;
typedef unsigned short u16;

typedef const __attribute__((address_space(1))) uint32_t* gptr_t;
typedef __attribute__((address_space(3))) uint32_t* lptr_t;

__device__ __forceinline__ u16 f2bf(float f) {
  union { float f; uint32_t u; } v; v.f = f;
  uint32_t r = v.u + 0x7FFFu + ((v.u >> 16) & 1u);  // RNE
  return (u16)(r >> 16);
}
__device__ __forceinline__ float bf2f(u16 b) {
  union { uint32_t u; float f; } v; v.u = ((uint32_t)b) << 16;
  return v.f;
}

// ---------------- k0: normalize prompts -> p_bf (bf16, padded to 1024 rows), ws[0,2MB)
__global__ __launch_bounds__(256) void k_prep_prompts(const float* __restrict__ prompts,
                                                      u16* __restrict__ p_bf) {
  const int r = blockIdx.x;   // 0..1023
  const int t = threadIdx.x;  // 256
  if (r >= 1000) {            // zero-fill pad rows
    if (t < 128) {
      s16x8 z = {0, 0, 0, 0, 0, 0, 0, 0};
      ((s16x8*)(p_bf + (size_t)r * 1024))[t] = z;
    }
    return;
  }
  float4 x = ((const float4*)(prompts + (size_t)r * 1024))[t];
  float ss = x.x * x.x + x.y * x.y + x.z * x.z + x.w * x.w;
  #pragma unroll
  for (int off = 32; off; off >>= 1) ss += __shfl_xor(ss, off);
  __shared__ float red[4];
  if ((t & 63) == 0) red[t >> 6] = ss;
  __syncthreads();
  float n = fmaxf(sqrtf(red[0] + red[1] + red[2] + red[3]), 1e-12f);
  float inv = 1.0f / n;
  u16* pb = p_bf + (size_t)r * 1024 + t * 4;
  pb[0] = f2bf(x.x * inv); pb[1] = f2bf(x.y * inv);
  pb[2] = f2bf(x.z * inv); pb[3] = f2bf(x.w * inv);
}

// ---------------- k0b: feat fp32 -> bf16 (scratch in d_out probs region; GEMM A operand)
__global__ __launch_bounds__(256) void k_feat(const float* __restrict__ feat,
                                              u16* __restrict__ out) {
  const size_t stride = (size_t)gridDim.x * 256;
  const size_t n4 = 67108864ull / 4;
  for (size_t j = (size_t)blockIdx.x * 256 + threadIdx.x; j < n4; j += stride) {
    float4 x = ((const float4*)feat)[j];
    ushort4 o;
    o.x = f2bf(x.x); o.y = f2bf(x.y); o.z = f2bf(x.z); o.w = f2bf(x.w);
    ((ushort4*)out)[j] = o;
  }
}

// ---------------- k1: bf16 MFMA GEMM  sims[n][c] = sum_k A[n][k]*B[c][k]
// m97 structure: 128x128 tile, BK=32, 4 waves (2x2 of 64x64), 16x16x32 MFMA,
// global_load_lds width-16 staging, XCD-grouping tile swizzle.
__global__ __launch_bounds__(256) void k_sims(const u16* __restrict__ A,   // [65536][1024] bf16
                                              const u16* __restrict__ B,   // [1024][1024] bf16
                                              u16* __restrict__ C) {       // [65536][1000] bf16
  __shared__ u16 As[128 * 32];
  __shared__ u16 Bs[128 * 32];
  // XCD swizzle: HW round-robins blockIdx across 8 XCDs. Map so one XCD owns
  // contiguous logical tiles -> all 8 bn-tiles of an A-strip share one L2.
  const int bid = blockIdx.x;                       // grid = 4096 = 8 * 512
  const int lg = (bid & 7) * 512 + (bid >> 3);      // bijective
  const int bn = lg & 7;
  const int bm = lg >> 3;
  const int t = threadIdx.x;
  const int w = t >> 6, l = t & 63;
  const int wm = (w >> 1) * 64, wn = (w & 1) * 64;
  const int lrow = l & 15, lko = l >> 4;

  f32x4 zero4 = {0.f, 0.f, 0.f, 0.f};
  f32x4 acc[4][4];
  #pragma unroll
  for (int i = 0; i < 4; i++)
    #pragma unroll
    for (int j = 0; j < 4; j++) acc[i][j] = zero4;

  const int srow = t >> 2;          // 0..63
  const int scol = (t & 3) * 8;     // 0,8,16,24  -> LDS byte offset = t*16 (linear per wave)

  for (int k0 = 0; k0 < 1024; k0 += 32) {
    __syncthreads();  // WAR: previous tile consumed
    #pragma unroll
    for (int i = 0; i < 2; i++) {
      int row = i * 64 + srow;
      const u16* ga = A + (size_t)(bm * 128 + row) * 1024 + k0 + scol;
      __builtin_amdgcn_global_load_lds((gptr_t)ga, (lptr_t)&As[row * 32 + scol], 16, 0, 0);
    }
    #pragma unroll
    for (int i = 0; i < 2; i++) {
      int row = i * 64 + srow;
      const u16* gb = B + (size_t)(bn * 128 + row) * 1024 + k0 + scol;
      __builtin_amdgcn_global_load_lds((gptr_t)gb, (lptr_t)&Bs[row * 32 + scol], 16, 0, 0);
    }
    __syncthreads();  // RAW: staging complete
    s16x8 a[4], b[4];
    #pragma unroll
    for (int mi = 0; mi < 4; mi++) a[mi] = *(const s16x8*)&As[(wm + mi * 16 + lrow) * 32 + lko * 8];
    #pragma unroll
    for (int ni = 0; ni < 4; ni++) b[ni] = *(const s16x8*)&Bs[(wn + ni * 16 + lrow) * 32 + lko * 8];
    #pragma unroll
    for (int mi = 0; mi < 4; mi++)
      #pragma unroll
      for (int ni = 0; ni < 4; ni++)
        acc[mi][ni] = __builtin_amdgcn_mfma_f32_16x16x32_bf16(a[mi], b[ni], acc[mi][ni], 0, 0, 0);
  }
  // epilogue: C/D layout col=lane&15, row=(lane>>4)*4+reg
  const int rbase = (l >> 4) * 4;
  #pragma unroll
  for (int mi = 0; mi < 4; mi++)
    #pragma unroll
    for (int ni = 0; ni < 4; ni++) {
      int gcol = bn * 128 + wn + ni * 16 + lrow;
      if (gcol >= 1000) continue;
      #pragma unroll
      for (int j = 0; j < 4; j++) {
        int grow = bm * 128 + wm + mi * 16 + rbase + j;
        C[(size_t)grow * 1000 + gcol] = f2bf(acc[mi][ni][j]);
      }
    }
}

// ---------------- k2: per-row top-8 screen + exact rescore + top-2 -> compact results in ws
__global__ __launch_bounds__(256) void k_topk(const float* __restrict__ feat,
                                              const float* __restrict__ prompts,
                                              const u16* __restrict__ sims,
                                              int2* __restrict__ resc,
                                              float2* __restrict__ resw) {
  const int l = threadIdx.x & 63;
  const int row = blockIdx.x * 4 + (threadIdx.x >> 6);
  const u16* srow_p = sims + (size_t)row * 1000;
  const float NEG = -3.0e38f;
  // strided sims load: lane l owns cols {l, l+64, ..., l+960}
  float s[16];
  #pragma unroll
  for (int jj = 0; jj < 16; jj++) {
    int c = l + 64 * jj;
    s[jj] = (c < 1000) ? bf2f(srow_p[c]) : NEG;
  }
  // top-8 by staged sims (tie -> lower col)
  int cand[8];
  uint32_t taken = 0;
  #pragma unroll
  for (int it = 0; it < 8; it++) {
    float bv = NEG; int bj = 0;
    #pragma unroll
    for (int j = 0; j < 16; j++) {
      bool ok = !((taken >> j) & 1u) && (s[j] > bv);
      if (ok) { bv = s[j]; bj = j; }
    }
    int bc = l + 64 * bj;
    #pragma unroll
    for (int off = 32; off; off >>= 1) {
      float ov = __shfl_xor(bv, off);
      int oc = __shfl_xor(bc, off);
      if (ov > bv || (ov == bv && oc < bc)) { bv = ov; bc = oc; }
    }
    cand[it] = (bc < 1000) ? bc : 999;
    if ((bc & 63) == l) taken |= (1u << (bc >> 6));
  }
  // feat row, norm
  const int base = l * 16;
  float q[16];
  const float4* fr = (const float4*)(feat + (size_t)row * 1024 + base);
  #pragma unroll
  for (int g = 0; g < 4; g++) {
    float4 x = fr[g];
    q[g * 4 + 0] = x.x; q[g * 4 + 1] = x.y; q[g * 4 + 2] = x.z; q[g * 4 + 3] = x.w;
  }
  float qq = 0.f;
  #pragma unroll
  for (int e = 0; e < 16; e++) qq += q[e] * q[e];
  #pragma unroll
  for (int off = 32; off; off >>= 1) qq += __shfl_xor(qq, off);
  float rn = 1.0f / fmaxf(sqrtf(qq), 1e-12f);
  // exact fp32 rescore (raw prompts, on-the-fly norm)
  float sc[8];
  #pragma unroll
  for (int i = 0; i < 8; i++) {
    const float4* pr = (const float4*)(prompts + (size_t)cand[i] * 1024 + base);
    float d = 0.f, nn = 0.f;
    #pragma unroll
    for (int g = 0; g < 4; g++) {
      float4 x = pr[g];
      d += q[g * 4 + 0] * x.x; d += q[g * 4 + 1] * x.y;
      d += q[g * 4 + 2] * x.z; d += q[g * 4 + 3] * x.w;
      nn += x.x * x.x + x.y * x.y + x.z * x.z + x.w * x.w;
    }
    #pragma unroll
    for (int off = 32; off; off >>= 1) {
      d += __shfl_xor(d, off);
      nn += __shfl_xor(nn, off);
    }
    sc[i] = d * rn / fmaxf(sqrtf(nn), 1e-12f);
  }
  // top-2 among exact scores (tie -> lower class index)
  int i1 = 0;
  #pragma unroll
  for (int i = 1; i < 8; i++)
    if (sc[i] > sc[i1] || (sc[i] == sc[i1] && cand[i] < cand[i1])) i1 = i;
  int i2 = (i1 == 0) ? 1 : 0;
  #pragma unroll
  for (int i = 0; i < 8; i++) {
    if (i == i1) continue;
    if (sc[i] > sc[i2] || (sc[i] == sc[i2] && cand[i] < cand[i2])) i2 = i;
  }
  int c1 = cand[i1], c2 = cand[i2];
  float e = expf(fminf(sc[i2] - sc[i1], 0.0f) * (1.0f / 0.07f));  // (0,1]
  float w1 = 1.0f / (1.0f + e);
  float w2 = e / (1.0f + e);
  if (l == 0) {
    resc[row] = make_int2(c1, c2);
    resw[row] = make_float2(w1, w2);
  }
}

// ---------------- k3: expand results -> float32 outputs (one block per row)
__global__ __launch_bounds__(256) void k_write(const float* __restrict__ prompts,
                                               const int2* __restrict__ resc,
                                               const float2* __restrict__ resw,
                                               float* __restrict__ mixed,
                                               float* __restrict__ probs) {
  const int row = blockIdx.x;
  const int t = threadIdx.x;
  int2 cc = resc[row];
  float2 ww = resw[row];
  const float4* P1 = (const float4*)(prompts + (size_t)cc.x * 1024);
  const float4* P2 = (const float4*)(prompts + (size_t)cc.y * 1024);
  float4 a = P1[t], b = P2[t];
  float4 o;
  o.x = ww.x * a.x + ww.y * b.x;
  o.y = ww.x * a.y + ww.y * b.y;
  o.z = ww.x * a.z + ww.y * b.z;
  o.w = ww.x * a.w + ww.y * b.w;
  ((float4*)(mixed + (size_t)row * 1024))[t] = o;
  if (t < 250) {
    const int base = t * 4;
    float4 z;
    z.x = (base + 0 == cc.x) ? ww.x : ((base + 0 == cc.y) ? ww.y : 0.0f);
    z.y = (base + 1 == cc.x) ? ww.x : ((base + 1 == cc.y) ? ww.y : 0.0f);
    z.z = (base + 2 == cc.x) ? ww.x : ((base + 2 == cc.y) ? ww.y : 0.0f);
    z.w = (base + 3 == cc.x) ? ww.x : ((base + 3 == cc.y) ? ww.y : 0.0f);
    ((float4*)(probs + (size_t)row * 1000))[t] = z;
  }
}

extern "C" void kernel_launch(void* const* d_in, const int* in_sizes, int n_in,
                              void* d_out, int out_size, void* d_ws, size_t ws_size,
                              hipStream_t stream) {
  // identify inputs by element count, not position
  int fi = 0, pi = 1;
  for (int i = 0; i < n_in; i++) {
    if (in_sizes[i] == 67108864) fi = i;
    else if (in_sizes[i] == 1024000) pi = i;
  }
  const float* feat = (const float*)d_in[fi];
  const float* prompts = (const float*)d_in[pi];

  // outputs are FLOAT32: mixed [65536*1024], probs [65536*1000]
  float* mixed = (float*)d_out;
  float* probs = mixed + 67108864ull;

  // ws: [0,2MB) bf16 prompt table; [2MB,2.5MB) int2 classes; [2.5MB,3MB) float2 weights
  u16* p_bf = (u16*)d_ws;
  int2* resc = (int2*)((char*)d_ws + (2ull << 20));
  float2* resw = (float2*)((char*)d_ws + (2ull << 20) + (512ull << 10));

  // scratch inside d_out (stream-ordered, later fully overwritten by k_write):
  //   bf16 sims  at start of mixed region  (131 MB < 268 MB)
  //   bf16 feat  at start of probs region  (134 MB < 262 MB)
  u16* sims = (u16*)d_out;
  u16* feat_bf = (u16*)probs;

  hipLaunchKernelGGL(k_prep_prompts, dim3(1024), dim3(256), 0, stream, prompts, p_bf);
  hipLaunchKernelGGL(k_feat, dim3(2048), dim3(256), 0, stream, feat, feat_bf);
  hipLaunchKernelGGL(k_sims, dim3(4096), dim3(256), 0, stream, feat_bf, p_bf, sims);
  hipLaunchKernelGGL(k_topk, dim3(16384), dim3(256), 0, stream, feat, prompts, sims, resc, resw);
  hipLaunchKernelGGL(k_write, dim3(65536), dim3(256), 0, stream, prompts, resc, resw, mixed, probs);
}

// Round 8
// 543.479 us; speedup vs baseline: 1.4160x; 1.3129x over previous
//
#include <hip/hip_runtime.h>
#include <cstdint>

using f32x4 = __attribute__((ext_vector_type(4))) float;
using s16x8 = __attribute__((ext_vector_type(8))) short;
typedef unsigned short u16;

typedef const __attribute__((address_space(1))) uint32_t* gptr_t;
typedef __attribute__((address_space(3))) uint32_t* lptr_t;

__device__ __forceinline__ u16 f2bf(float f) {
  union { float f; uint32_t u; } v; v.f = f;
  uint32_t r = v.u + 0x7FFFu + ((v.u >> 16) & 1u);  // RNE
  return (u16)(r >> 16);
}
__device__ __forceinline__ float bf2f(u16 b) {
  union { uint32_t u; float f; } v; v.u = ((uint32_t)b) << 16;
  return v.f;
}

// ---------------- k0: normalize prompts -> p_bf (bf16, padded to 1024 rows), ws[0,2MB)
__global__ __launch_bounds__(256) void k_prep_prompts(const float* __restrict__ prompts,
                                                      u16* __restrict__ p_bf) {
  const int r = blockIdx.x;   // 0..1023
  const int t = threadIdx.x;  // 256
  if (r >= 1000) {            // zero-fill pad rows
    if (t < 128) {
      s16x8 z = {0, 0, 0, 0, 0, 0, 0, 0};
      ((s16x8*)(p_bf + (size_t)r * 1024))[t] = z;
    }
    return;
  }
  float4 x = ((const float4*)(prompts + (size_t)r * 1024))[t];
  float ss = x.x * x.x + x.y * x.y + x.z * x.z + x.w * x.w;
  #pragma unroll
  for (int off = 32; off; off >>= 1) ss += __shfl_xor(ss, off);
  __shared__ float red[4];
  if ((t & 63) == 0) red[t >> 6] = ss;
  __syncthreads();
  float n = fmaxf(sqrtf(red[0] + red[1] + red[2] + red[3]), 1e-12f);
  float inv = 1.0f / n;
  u16* pb = p_bf + (size_t)r * 1024 + t * 4;
  pb[0] = f2bf(x.x * inv); pb[1] = f2bf(x.y * inv);
  pb[2] = f2bf(x.z * inv); pb[3] = f2bf(x.w * inv);
}

// ---------------- k0b: feat fp32 -> bf16 (scratch in d_out probs region; GEMM A operand)
__global__ __launch_bounds__(256) void k_feat(const float* __restrict__ feat,
                                              u16* __restrict__ out) {
  const size_t stride = (size_t)gridDim.x * 256;
  const size_t n4 = 67108864ull / 4;
  for (size_t j = (size_t)blockIdx.x * 256 + threadIdx.x; j < n4; j += stride) {
    float4 x = ((const float4*)feat)[j];
    ushort4 o;
    o.x = f2bf(x.x); o.y = f2bf(x.y); o.z = f2bf(x.z); o.w = f2bf(x.w);
    ((ushort4*)out)[j] = o;
  }
}

// ---------------- k1: bf16 MFMA GEMM  sims[n][c] = sum_k A[n][k]*B[c][k]
// m97 structure: 128x128 tile, BK=32, 4 waves, 16x16x32 MFMA, global_load_lds, XCD swizzle
__global__ __launch_bounds__(256) void k_sims(const u16* __restrict__ A,   // [65536][1024] bf16
                                              const u16* __restrict__ B,   // [1024][1024] bf16
                                              u16* __restrict__ C) {       // [65536][1000] bf16
  __shared__ u16 As[128 * 32];
  __shared__ u16 Bs[128 * 32];
  const int bid = blockIdx.x;                       // grid = 4096 = 8 * 512
  const int lg = (bid & 7) * 512 + (bid >> 3);      // bijective XCD-grouping swizzle
  const int bn = lg & 7;
  const int bm = lg >> 3;
  const int t = threadIdx.x;
  const int w = t >> 6, l = t & 63;
  const int wm = (w >> 1) * 64, wn = (w & 1) * 64;
  const int lrow = l & 15, lko = l >> 4;

  f32x4 zero4 = {0.f, 0.f, 0.f, 0.f};
  f32x4 acc[4][4];
  #pragma unroll
  for (int i = 0; i < 4; i++)
    #pragma unroll
    for (int j = 0; j < 4; j++) acc[i][j] = zero4;

  const int srow = t >> 2;          // 0..63
  const int scol = (t & 3) * 8;     // 0,8,16,24

  for (int k0 = 0; k0 < 1024; k0 += 32) {
    __syncthreads();  // WAR: previous tile consumed
    #pragma unroll
    for (int i = 0; i < 2; i++) {
      int row = i * 64 + srow;
      const u16* ga = A + (size_t)(bm * 128 + row) * 1024 + k0 + scol;
      __builtin_amdgcn_global_load_lds((gptr_t)ga, (lptr_t)&As[row * 32 + scol], 16, 0, 0);
    }
    #pragma unroll
    for (int i = 0; i < 2; i++) {
      int row = i * 64 + srow;
      const u16* gb = B + (size_t)(bn * 128 + row) * 1024 + k0 + scol;
      __builtin_amdgcn_global_load_lds((gptr_t)gb, (lptr_t)&Bs[row * 32 + scol], 16, 0, 0);
    }
    __syncthreads();  // RAW: staging complete
    s16x8 a[4], b[4];
    #pragma unroll
    for (int mi = 0; mi < 4; mi++) a[mi] = *(const s16x8*)&As[(wm + mi * 16 + lrow) * 32 + lko * 8];
    #pragma unroll
    for (int ni = 0; ni < 4; ni++) b[ni] = *(const s16x8*)&Bs[(wn + ni * 16 + lrow) * 32 + lko * 8];
    #pragma unroll
    for (int mi = 0; mi < 4; mi++)
      #pragma unroll
      for (int ni = 0; ni < 4; ni++)
        acc[mi][ni] = __builtin_amdgcn_mfma_f32_16x16x32_bf16(a[mi], b[ni], acc[mi][ni], 0, 0, 0);
  }
  const int rbase = (l >> 4) * 4;
  #pragma unroll
  for (int mi = 0; mi < 4; mi++)
    #pragma unroll
    for (int ni = 0; ni < 4; ni++) {
      int gcol = bn * 128 + wn + ni * 16 + lrow;
      if (gcol >= 1000) continue;
      #pragma unroll
      for (int j = 0; j < 4; j++) {
        int grow = bm * 128 + wm + mi * 16 + rbase + j;
        C[(size_t)grow * 1000 + gcol] = f2bf(acc[mi][ni][j]);
      }
    }
}

// ---------------- k2: per-row threshold-survivor screen + exact rescore -> probs + compact
// Screen margin in STORED (feat-unnormalized) scale: sims_stored = dot(bf16(feat), p_bf),
// sigma ~ 1.0, top values 2..5. Deviation stored-vs-exact: bf16 storage half-ulp <= 3.1e-2
// (|s|<8) + dot quant error 8sigma ~ 2.6e-2 -> 2*delta ~ 0.115. T = M2 - 0.25 (>2x safety);
// expected survivors ~ 3.6/row. (Round 7 used 2.5e-3 — cosine-scale number, wrong by 32x.)
__global__ __launch_bounds__(256) void k_topk(const float* __restrict__ feat,
                                              const float* __restrict__ prompts,
                                              const u16* __restrict__ sims,
                                              int2* __restrict__ resc,
                                              float2* __restrict__ resw,
                                              float* __restrict__ probs) {
  const int l = threadIdx.x & 63;
  const int row = blockIdx.x * 4 + (threadIdx.x >> 6);
  const u16* srow = sims + (size_t)row * 1000;
  const float NEG = -3.0e38f;
  // paired u32 sims load: slot jj holds col 2l + 128*(jj>>1) + (jj&1); covers 0..1023
  float s[16];
  #pragma unroll
  for (int j = 0; j < 8; j++) {
    int c = 2 * l + 128 * j;
    if (c + 1 < 1000) {
      uint32_t v = *(const uint32_t*)(srow + c);
      s[2 * j] = bf2f((u16)(v & 0xFFFFu));
      s[2 * j + 1] = bf2f((u16)(v >> 16));
    } else {
      s[2 * j] = (c < 1000) ? bf2f(srow[c]) : NEG;
      s[2 * j + 1] = NEG;
    }
  }
  // per-lane top-2
  float a1 = NEG, a2 = NEG;
  #pragma unroll
  for (int j = 0; j < 16; j++) {
    float v = s[j];
    bool g1 = v > a1;
    a2 = g1 ? a1 : fmaxf(a2, v);
    a1 = g1 ? v : a1;
  }
  // wave top-2 butterfly
  #pragma unroll
  for (int off = 32; off; off >>= 1) {
    float b1 = __shfl_xor(a1, off), b2 = __shfl_xor(a2, off);
    float m1 = fmaxf(a1, b1);
    float m2 = fmaxf(fminf(a1, b1), fmaxf(a2, b2));
    a1 = m1; a2 = m2;
  }
  const float T = a2 - 0.25f;   // stored-scale margin (see header comment)
  uint32_t mask = 0;
  #pragma unroll
  for (int j = 0; j < 16; j++) {
    int c = 2 * l + 128 * (j >> 1) + (j & 1);
    if (c < 1000 && s[j] >= T) mask |= (1u << j);
  }
  // feat row (contiguous-16 per lane), row norm
  const int base = l * 16;
  float q[16];
  const float4* fr = (const float4*)(feat + (size_t)row * 1024 + base);
  #pragma unroll
  for (int g = 0; g < 4; g++) {
    float4 x = fr[g];
    q[g * 4 + 0] = x.x; q[g * 4 + 1] = x.y; q[g * 4 + 2] = x.z; q[g * 4 + 3] = x.w;
  }
  float qq = 0.f;
  #pragma unroll
  for (int e = 0; e < 16; e++) qq += q[e] * q[e];
  #pragma unroll
  for (int off = 32; off; off >>= 1) qq += __shfl_xor(qq, off);
  float rn = 1.0f / fmaxf(sqrtf(qq), 1e-12f);
  // survivor loop: exact fp32 rescore, running top-2 with lower-index tie-break
  float s1 = NEG, s2 = NEG;
  int c1 = 0x40000000, c2 = 0x40000000;
  while (true) {
    unsigned long long act = __ballot(mask != 0);
    if (!act) break;
    int ln = (int)__ffsll(act) - 1;
    int fj = __ffs(mask) - 1;                       // lowest candidate bit (valid if mask!=0)
    int myc = 2 * l + 128 * (fj >> 1) + (fj & 1);
    int bc = __shfl(myc, ln);
    if (l == ln) mask &= (mask - 1);
    const float4* pr = (const float4*)(prompts + (size_t)bc * 1024 + base);
    float d = 0.f, nn = 0.f;
    #pragma unroll
    for (int g = 0; g < 4; g++) {
      float4 x = pr[g];
      d += q[g * 4 + 0] * x.x; d += q[g * 4 + 1] * x.y;
      d += q[g * 4 + 2] * x.z; d += q[g * 4 + 3] * x.w;
      nn += x.x * x.x + x.y * x.y + x.z * x.z + x.w * x.w;
    }
    #pragma unroll
    for (int off = 32; off; off >>= 1) {
      d += __shfl_xor(d, off);
      nn += __shfl_xor(nn, off);
    }
    float sc = d * rn / fmaxf(sqrtf(nn), 1e-12f);
    bool b1w = (sc > s1) || (sc == s1 && bc < c1);
    bool b2w = (sc > s2) || (sc == s2 && bc < c2);
    if (b1w) { s2 = s1; c2 = c1; s1 = sc; c1 = bc; }
    else if (b2w) { s2 = sc; c2 = bc; }
  }
  float e = expf(fminf(s2 - s1, 0.0f) * (1.0f / 0.07f));  // (0,1]
  float w1 = 1.0f / (1.0f + e);
  float w2 = e / (1.0f + e);
  // probs row write (strided, coalesced): zeros + two weights
  float* prow = probs + (size_t)row * 1000;
  #pragma unroll
  for (int j = 0; j < 16; j++) {
    int c = l + 64 * j;
    if (c < 1000) prow[c] = (c == c1) ? w1 : ((c == c2) ? w2 : 0.0f);
  }
  if (l == 0) {
    resc[row] = make_int2(c1, c2);
    resw[row] = make_float2(w1, w2);
  }
}

// ---------------- k3: mixed = w1*P1 + w2*P2 (one block per row; overwrites sims scratch)
__global__ __launch_bounds__(256) void k_write2(const float* __restrict__ prompts,
                                                const int2* __restrict__ resc,
                                                const float2* __restrict__ resw,
                                                float* __restrict__ mixed) {
  const int row = blockIdx.x;
  const int t = threadIdx.x;
  int2 cc = resc[row];
  float2 ww = resw[row];
  const float4* P1 = (const float4*)(prompts + (size_t)cc.x * 1024);
  const float4* P2 = (const float4*)(prompts + (size_t)cc.y * 1024);
  float4 a = P1[t], b = P2[t];
  float4 o;
  o.x = ww.x * a.x + ww.y * b.x;
  o.y = ww.x * a.y + ww.y * b.y;
  o.z = ww.x * a.z + ww.y * b.z;
  o.w = ww.x * a.w + ww.y * b.w;
  ((float4*)(mixed + (size_t)row * 1024))[t] = o;
}

extern "C" void kernel_launch(void* const* d_in, const int* in_sizes, int n_in,
                              void* d_out, int out_size, void* d_ws, size_t ws_size,
                              hipStream_t stream) {
  // identify inputs by element count, not position
  int fi = 0, pi = 1;
  for (int i = 0; i < n_in; i++) {
    if (in_sizes[i] == 67108864) fi = i;
    else if (in_sizes[i] == 1024000) pi = i;
  }
  const float* feat = (const float*)d_in[fi];
  const float* prompts = (const float*)d_in[pi];

  // outputs are FLOAT32: mixed [65536*1024], probs [65536*1000]
  float* mixed = (float*)d_out;
  float* probs = mixed + 67108864ull;

  // ws: [0,2MB) bf16 prompt table; [2MB,2.5MB) int2 classes; [2.5MB,3MB) float2 weights
  u16* p_bf = (u16*)d_ws;
  int2* resc = (int2*)((char*)d_ws + (2ull << 20));
  float2* resw = (float2*)((char*)d_ws + (2ull << 20) + (512ull << 10));

  // scratch inside d_out (stream-ordered):
  //   bf16 sims  at start of mixed region (read by k_topk, overwritten by k_write2)
  //   bf16 feat  at start of probs region (read by k_sims, overwritten by k_topk's probs)
  u16* sims = (u16*)d_out;
  u16* feat_bf = (u16*)probs;

  hipLaunchKernelGGL(k_prep_prompts, dim3(1024), dim3(256), 0, stream, prompts, p_bf);
  hipLaunchKernelGGL(k_feat, dim3(2048), dim3(256), 0, stream, feat, feat_bf);
  hipLaunchKernelGGL(k_sims, dim3(4096), dim3(256), 0, stream, feat_bf, p_bf, sims);
  hipLaunchKernelGGL(k_topk, dim3(16384), dim3(256), 0, stream, feat, prompts, sims, resc, resw, probs);
  hipLaunchKernelGGL(k_write2, dim3(65536), dim3(256), 0, stream, prompts, resc, resw, mixed);
}